// Round 9
// baseline (131.415 us; speedup 1.0000x reference)
//
#include <hip/hip_runtime.h>
#include <stdint.h>

// Problem constants
#define KCB 8192      // codebook entries
#define DDIM 256      // latent dim
#define NROWS 16384   // 16*32*32 latent vectors
#define NELEM 4194304 // 16*256*32*32

typedef __attribute__((ext_vector_type(4))) int   i32x4;
typedef __attribute__((ext_vector_type(8))) int   i32x8;
typedef __attribute__((ext_vector_type(16))) float f32x16;

// Branchless fp4 e2m1 encode (RNE midpoint thresholds).
// grid: 0,0.5,1,1.5,2,3,4,6 ; code = #thresholds passed; sign at bit 3.
__device__ __forceinline__ unsigned enc_e2m1(float v) {
    float m = __builtin_fabsf(v);
    unsigned c = 0;
    c += (m >= 0.25f); c += (m >= 0.75f); c += (m >= 1.25f); c += (m >= 1.75f);
    c += (m >= 2.5f);  c += (m >= 3.5f);  c += (m >= 5.0f);
    return c | ((__float_as_uint(v) >> 28) & 8u);
}

// ---------------------------------------------------------------- fused prep
// fp4 fragment unit = 1 KB: lane L holds 16 contiguous bytes (32 nibbles) at
// unit*1024 + L*16; nibble j (k-slot) at dword j>>3, bit (j&7)*4. A and B use
// the IDENTICAL (lane,slot)->k bijection, so any within-lane k/bit permutation
// of the true MFMA operand layout cancels in the dot. d(k)=ks*64+(L>>5)*32+j.
// blocks [0,512):   z f32 -> Ab fp4 (A unit u: mb=u>>2 rows-of-32, ks=u&3)
//                   + zn2p[n*8+ks*2+half] = partial sum z^2 (32 d-els)
// blocks [512,768): emb f32 *32768 (range [-4,4]) -> Bb fp4
//                   (B unit u = CB*8 + nf*4 + ks; col = CB*64+nf*32+(L&31))
// blocks [768,832): minP init, loss init
__global__ void prep_kernel(const float* __restrict__ z,
                            const float* __restrict__ emb,
                            unsigned char* __restrict__ Ab,
                            unsigned char* __restrict__ Bb,
                            float* __restrict__ zn2p,
                            unsigned* __restrict__ minP,
                            float* __restrict__ loss) {
    int bz = blockIdx.x;
    int t  = threadIdx.x;
    if (bz < 512) {
        int u  = bz * 4 + (t >> 6);
        int L  = t & 63;
        int mb = u >> 2, ks = u & 3;
        int n  = mb * 32 + (L & 31);
        int d0 = ks * 64 + (L >> 5) * 32;
        const float* src = z + (n >> 10) * 262144 + (n & 1023) + d0 * 1024;
        float ss = 0.f;
        unsigned dw[4] = {0u, 0u, 0u, 0u};
        #pragma unroll
        for (int j = 0; j < 32; ++j) {
            float v = src[j * 1024];
            ss += v * v;
            dw[j >> 3] |= enc_e2m1(v) << ((j & 7) * 4);
        }
        zn2p[n * 8 + ks * 2 + (L >> 5)] = ss;
        i32x4 o; o[0] = (int)dw[0]; o[1] = (int)dw[1]; o[2] = (int)dw[2]; o[3] = (int)dw[3];
        *(i32x4*)(Ab + u * 1024 + L * 16) = o;
    } else if (bz < 768) {
        int u  = (bz - 512) * 4 + (t >> 6);   // CB*8 + nf*4 + ks
        int L  = t & 63;
        int CB = u >> 3, nf = (u >> 2) & 1, ks = u & 3;
        int n  = CB * 64 + nf * 32 + (L & 31);
        int d0 = ks * 64 + (L >> 5) * 32;
        const float* src = emb + n * DDIM + d0;
        unsigned dw[4] = {0u, 0u, 0u, 0u};
        #pragma unroll
        for (int j = 0; j < 32; ++j) {
            float v = src[j] * 32768.f;
            dw[j >> 3] |= enc_e2m1(v) << ((j & 7) * 4);
        }
        i32x4 o; o[0] = (int)dw[0]; o[1] = (int)dw[1]; o[2] = (int)dw[2]; o[3] = (int)dw[3];
        *(i32x4*)(Bb + u * 1024 + L * 16) = o;
    } else {
        int i = (bz - 768) * 256 + t;
        minP[i] = 0xFFFFFFFFu;
        if (i == 0) *loss = 0.0f;
    }
}

__device__ __forceinline__ i32x8 up8(i32x4 a) {
    i32x8 r;
    r[0] = a[0]; r[1] = a[1]; r[2] = a[2]; r[3] = a[3];
    r[4] = 0; r[5] = 0; r[6] = 0; r[7] = 0;
    return r;
}

__device__ __forceinline__ unsigned umin2(unsigned a, unsigned b) {
    return a < b ? a : b;
}

// ---------------------------------------------------------------- GEMM + argmin
// INVERTED RESIDENCY (vs R8): the 256-row x 256-k fp4 A-block is only 32 KB ->
// staged to LDS ONCE (one barrier pair for the whole kernel, not one per tile);
// B is register-resident (wave owns 128 cols: 4 nf x 4 ks x i32x4 = 64 VGPR,
// loaded once from the XCD-pinned L2 slice). Block: 512 thr = 8 waves, each
// wave computes its 128 cols x all 256 rows. LDS reads = 4 b128 per mf (A
// frag), 4x fewer than R8's B-tile reads; no per-tile barriers.
// Cross-wave row-min combine in LDS (minw), then one atomicMin per row.
// fp4 x fp4 (cbsz=4, blgp=4) 32x32x64 scaled MFMA, scales = 1.0.
// acc = 32768*(z.e), |acc| <~ 300: sc = 512 - acc > 0 -> float bits
// order-preserving; key = (bits & ~0x1FFF) | col, min_u32 reduce.
// C/D layout: col = lane&31, row = (reg&3) + 8*(reg>>2) + 4*(lane>>5).
__global__ __launch_bounds__(512, 2) void gemm_argmin_kernel(
        const unsigned char* __restrict__ Ab, const unsigned char* __restrict__ Bb,
        unsigned* __restrict__ minP) {
    __shared__ unsigned char ldsA[32768];
    __shared__ unsigned minw[2048];     // 8 waves x 256 rows
    int t  = threadIdx.x;
    int bx = blockIdx.x;               // 0..511
    int R  = bx >> 3;                  // 0..63 (256-row block)
    int ch = bx & 7;                   // col slice: XCD-aligned for L2 residency
    int w  = t >> 6, L = t & 63;
    int h  = L >> 5, l31 = L & 31;

    // stage the whole A block (32 KB) once; layout = global layout
    {
        const unsigned char* src = Ab + R * 32768 + t * 16;
        #pragma unroll
        for (int i = 0; i < 4; ++i)
            __builtin_amdgcn_global_load_lds(
                (const __attribute__((address_space(1))) void*)(src + i * 8192),
                (__attribute__((address_space(3))) void*)(&ldsA[t * 16 + i * 8192]),
                16, 0, 0);
    }

    // B resident: wave w owns cols ch*1024 + w*128 .. +127 (4 frags of 32)
    int colw = ch * 1024 + w * 128;
    i32x4 bf[4][4];
    #pragma unroll
    for (int nf = 0; nf < 4; ++nf) {
        int g = (colw >> 5) + nf;          // global 32-col frag index
        const unsigned char* base = Bb + ((g >> 1) * 8 + (g & 1) * 4) * 1024 + L * 16;
        #pragma unroll
        for (int ks = 0; ks < 4; ++ks)
            bf[nf][ks] = *(const i32x4*)(base + ks * 1024);
    }

    f32x16 zero16;
    #pragma unroll
    for (int r = 0; r < 16; ++r) zero16[r] = 0.f;

    __syncthreads();                   // A staged (barrier drains the DMA)

    for (int mf = 0; mf < 8; ++mf) {
        i32x4 afr[4];
        #pragma unroll
        for (int ks = 0; ks < 4; ++ks)
            afr[ks] = *(const i32x4*)(&ldsA[(mf * 4 + ks) * 1024 + L * 16]);

        f32x16 acc[4];
        #pragma unroll
        for (int nf = 0; nf < 4; ++nf)
            acc[nf] = __builtin_amdgcn_mfma_scale_f32_32x32x64_f8f6f4(
                up8(afr[0]), up8(bf[nf][0]), zero16, 4, 4, 0, 0x7F7F7F7F, 0, 0x7F7F7F7F);
        #pragma unroll
        for (int ks = 1; ks < 4; ++ks)
            #pragma unroll
            for (int nf = 0; nf < 4; ++nf)
                acc[nf] = __builtin_amdgcn_mfma_scale_f32_32x32x64_f8f6f4(
                    up8(afr[ks]), up8(bf[nf][ks]), acc[nf], 4, 4, 0, 0x7F7F7F7F, 0, 0x7F7F7F7F);

        unsigned mp[16];
        #pragma unroll
        for (int r = 0; r < 16; ++r) {
            unsigned k0 = (__float_as_uint(512.0f - acc[0][r]) & 0xFFFFE000u)
                        | (unsigned)(colw + l31);
            unsigned k1 = (__float_as_uint(512.0f - acc[1][r]) & 0xFFFFE000u)
                        | (unsigned)(colw + 32 + l31);
            unsigned k2 = (__float_as_uint(512.0f - acc[2][r]) & 0xFFFFE000u)
                        | (unsigned)(colw + 64 + l31);
            unsigned k3 = (__float_as_uint(512.0f - acc[3][r]) & 0xFFFFE000u)
                        | (unsigned)(colw + 96 + l31);
            mp[r] = umin2(umin2(k0, k1), umin2(k2, k3));
        }
        // reduce over the 32 column-lanes (xor stays within the h-half)
        #pragma unroll
        for (int ml = 1; ml <= 16; ml <<= 1)
            #pragma unroll
            for (int r = 0; r < 16; ++r) {
                unsigned o = __shfl_xor(mp[r], ml);
                mp[r] = umin2(mp[r], o);
            }
        if (l31 == 0) {
            #pragma unroll
            for (int r = 0; r < 16; ++r)
                minw[w * 256 + mf * 32 + (r & 3) + 8 * (r >> 2) + 4 * h] = mp[r];
        }
    }

    __syncthreads();                   // all waves' minw written
    if (t < 256) {
        unsigned m = minw[t];
        #pragma unroll
        for (int w2 = 1; w2 < 8; ++w2)
            m = umin2(m, minw[w2 * 256 + t]);
        atomicMin(&minP[R * 256 + t], m);
    }
}

// ---------------------------------------------------------------- finalize
// out[b,d,h,w] = emb[idx[n]][d].  Loss computed ANALYTICALLY (no z reads):
// sum((zq-z)^2) = sum||z||^2 + sum(zq^2) - 2*dot, dot from the argmin key:
// dot = (512 - sc_q)/32768, sc_q = float(key & ~0x1FFF).
__global__ void finalize_kernel(const float* __restrict__ emb,
                                const float* __restrict__ zn2p,
                                const unsigned* __restrict__ minP,
                                float* __restrict__ out,
                                float* __restrict__ loss) {
    __shared__ float ez[32 * 257];
    __shared__ int   idxs[32];
    __shared__ float wsum[4];
    int t  = threadIdx.x;
    int bh = blockIdx.x;                 // b = bh>>5, h = bh&31
    float rterm = 0.f;
    if (t < 32) {
        int n = bh * 32 + t;
        unsigned key = minP[n];
        idxs[t] = (int)(key & 0x1FFFu);
        float sc_q = __uint_as_float(key & 0xFFFFE000u);
        float4 p0 = *(const float4*)(zn2p + n * 8);
        float4 p1 = *(const float4*)(zn2p + n * 8 + 4);
        float zn2 = p0.x + p0.y + p0.z + p0.w + p1.x + p1.y + p1.z + p1.w;
        rterm = zn2 - (512.0f - sc_q) * 6.103515625e-5f;   // - 2*dot
    }
    __syncthreads();
    {   // gather 32 embedding rows, coalesced along d, LDS-transposed
        int f = t & 63, rl = t >> 6;
        #pragma unroll
        for (int i = 0; i < 8; ++i) {
            int wl  = rl + i * 4;
            int idx = idxs[wl];
            float4 v = *(const float4*)(emb + idx * DDIM + f * 4);
            float* dst = &ez[wl * 257 + f * 4];
            dst[0] = v.x; dst[1] = v.y; dst[2] = v.z; dst[3] = v.w;
        }
    }
    __syncthreads();
    int wq = t & 31;                     // w
    int dg = t >> 5;                     // 0..7
    int off0 = (bh >> 5) * 262144 + (bh & 31) * 32 + wq;
    const float* ezrow = &ez[wq * 257];
    float lacc = rterm;
    #pragma unroll
    for (int it = 0; it < 32; ++it) {
        int d = it * 8 + dg;
        float zq = ezrow[d];
        out[off0 + d * 1024] = zq;
        lacc += zq * zq;                 // accumulates sum||e_idx||^2
    }
    #pragma unroll
    for (int ml = 1; ml <= 32; ml <<= 1) lacc += __shfl_xor(lacc, ml);
    if ((t & 63) == 0) wsum[t >> 6] = lacc;
    __syncthreads();
    if (t == 0) {
        float tot = wsum[0] + wsum[1] + wsum[2] + wsum[3];
        atomicAdd(loss, tot * (1.25f / (float)NELEM));
    }
}

// ---------------------------------------------------------------- launch
extern "C" void kernel_launch(void* const* d_in, const int* in_sizes, int n_in,
                              void* d_out, int out_size, void* d_ws, size_t ws_size,
                              hipStream_t stream) {
    const float* z   = (const float*)d_in[0];
    const float* emb = (const float*)d_in[1];
    float* out  = (float*)d_out;
    float* loss = out + NELEM;

    // ws: minP 64 KB + zn2p 512 KB. Big scratch (Ab 2MB @0, Bb 1MB @2MB)
    // overlaid on d_out (16.78 MB): consumed by gemm, then finalize overwrites.
    char* ws = (char*)d_ws;
    unsigned* minP = (unsigned*)ws;                           // 64 KB
    float* zn2p = (float*)(ws + 65536);                       // 512 KB
    unsigned char* Ab = (unsigned char*)d_out;                // 2 MB (2048 units)
    unsigned char* Bb = Ab + (size_t)NROWS * DDIM / 2;        // 1 MB (1024 units)

    hipLaunchKernelGGL(prep_kernel,        dim3(832), dim3(256), 0, stream,
                       z, emb, Ab, Bb, zn2p, minP, loss);
    hipLaunchKernelGGL(gemm_argmin_kernel, dim3(512), dim3(512), 0, stream,
                       Ab, Bb, minP);
    hipLaunchKernelGGL(finalize_kernel,    dim3(512), dim3(256), 0, stream,
                       emb, zn2p, minP, out, loss);
}

// Round 10
// 119.402 us; speedup vs baseline: 1.1006x; 1.1006x over previous
//
#include <hip/hip_runtime.h>
#include <stdint.h>

// Problem constants
#define KCB 8192      // codebook entries
#define DDIM 256      // latent dim
#define NROWS 16384   // 16*32*32 latent vectors
#define NELEM 4194304 // 16*256*32*32

typedef __attribute__((ext_vector_type(4))) int   i32x4;
typedef __attribute__((ext_vector_type(8))) int   i32x8;
typedef __attribute__((ext_vector_type(16))) float f32x16;

// Branchless fp4 e2m1 encode (RNE midpoint thresholds).
// grid: 0,0.5,1,1.5,2,3,4,6 ; code = #thresholds passed; sign at bit 3.
__device__ __forceinline__ unsigned enc_e2m1(float v) {
    float m = __builtin_fabsf(v);
    unsigned c = 0;
    c += (m >= 0.25f); c += (m >= 0.75f); c += (m >= 1.25f); c += (m >= 1.75f);
    c += (m >= 2.5f);  c += (m >= 3.5f);  c += (m >= 5.0f);
    return c | ((__float_as_uint(v) >> 28) & 8u);
}

// ---------------------------------------------------------------- fused prep
// fp4 fragment unit = 1 KB: lane L holds 16 contiguous bytes (32 nibbles) at
// unit*1024 + L*16; nibble j (k-slot) at dword j>>3, bit (j&7)*4. A and B use
// the IDENTICAL (lane,slot)->k bijection, so any within-lane k/bit permutation
// of the true MFMA operand layout cancels in the dot. d(k)=ks*64+(L>>5)*32+j.
// blocks [0,512):   z f32 -> Ab fp4 (A unit u: mb=u>>2 rows-of-32, ks=u&3)
//                   + zn2p[n*8+ks*2+half] = partial sum z^2 (32 d-els)
// blocks [512,768): emb f32 *32768 (range [-4,4]) -> Bb fp4
//                   (B unit u = CB*8 + nf*4 + ks; col = CB*64+nf*32+(L&31))
// blocks [768,832): minP init, loss init
__global__ void prep_kernel(const float* __restrict__ z,
                            const float* __restrict__ emb,
                            unsigned char* __restrict__ Ab,
                            unsigned char* __restrict__ Bb,
                            float* __restrict__ zn2p,
                            unsigned* __restrict__ minP,
                            float* __restrict__ loss) {
    int bz = blockIdx.x;
    int t  = threadIdx.x;
    if (bz < 512) {
        int u  = bz * 4 + (t >> 6);
        int L  = t & 63;
        int mb = u >> 2, ks = u & 3;
        int n  = mb * 32 + (L & 31);
        int d0 = ks * 64 + (L >> 5) * 32;
        const float* src = z + (n >> 10) * 262144 + (n & 1023) + d0 * 1024;
        float ss = 0.f;
        unsigned dw[4] = {0u, 0u, 0u, 0u};
        #pragma unroll
        for (int j = 0; j < 32; ++j) {
            float v = src[j * 1024];
            ss += v * v;
            dw[j >> 3] |= enc_e2m1(v) << ((j & 7) * 4);
        }
        zn2p[n * 8 + ks * 2 + (L >> 5)] = ss;
        i32x4 o; o[0] = (int)dw[0]; o[1] = (int)dw[1]; o[2] = (int)dw[2]; o[3] = (int)dw[3];
        *(i32x4*)(Ab + u * 1024 + L * 16) = o;
    } else if (bz < 768) {
        int u  = (bz - 512) * 4 + (t >> 6);   // CB*8 + nf*4 + ks
        int L  = t & 63;
        int CB = u >> 3, nf = (u >> 2) & 1, ks = u & 3;
        int n  = CB * 64 + nf * 32 + (L & 31);
        int d0 = ks * 64 + (L >> 5) * 32;
        const float* src = emb + n * DDIM + d0;
        unsigned dw[4] = {0u, 0u, 0u, 0u};
        #pragma unroll
        for (int j = 0; j < 32; ++j) {
            float v = src[j] * 32768.f;
            dw[j >> 3] |= enc_e2m1(v) << ((j & 7) * 4);
        }
        i32x4 o; o[0] = (int)dw[0]; o[1] = (int)dw[1]; o[2] = (int)dw[2]; o[3] = (int)dw[3];
        *(i32x4*)(Bb + u * 1024 + L * 16) = o;
    } else {
        int i = (bz - 768) * 256 + t;
        minP[i] = 0xFFFFFFFFu;
        if (i == 0) *loss = 0.0f;
    }
}

__device__ __forceinline__ i32x8 up8(i32x4 a) {
    i32x8 r;
    r[0] = a[0]; r[1] = a[1]; r[2] = a[2]; r[3] = a[3];
    r[4] = 0; r[5] = 0; r[6] = 0; r[7] = 0;
    return r;
}

__device__ __forceinline__ unsigned umin2(unsigned a, unsigned b) {
    return a < b ? a : b;
}

// ---------------------------------------------------------------- GEMM + argmin
// B-SLICE LDS-RESIDENT, ONE BARRIER TOTAL. Block = 512 thr (8 waves) owns
// 512 rows x 512 cols. The block's B slice (512 cols x 256 k fp4) is exactly
// 64 KB: staged to LDS ONCE via DMA, then the K/N loop has NO barriers and
// LDS is never rewritten (no WAR hazards) - waves free-run, MFMA-dominated.
// A is register-light (af[2][4] = 32 VGPR, the R8-proven amount; R9 showed
// large B-resident register sets get demoted by the allocator).
// Grid 512 = 32 row-blocks x 16 ch slices; XCD k hosts ch in {k, k+8} ->
// 128 KB of B per XCD L2. fp4 x fp4 (cbsz=4, blgp=4) 32x32x64 scaled MFMA.
// acc = 32768*(z.e), |acc| <~ 300: sc = 512 - acc > 0 -> float bits
// order-preserving; key = (bits & ~0x1FFF) | col, min_u32 reduce.
// C/D layout: col = lane&31, row = (reg&3) + 8*(reg>>2) + 4*(lane>>5).
__global__ __launch_bounds__(512, 2) void gemm_argmin_kernel(
        const unsigned char* __restrict__ Ab, const unsigned char* __restrict__ Bb,
        unsigned* __restrict__ minP) {
    __shared__ unsigned char ldsB[65536];
    int t  = threadIdx.x;
    int bx = blockIdx.x;               // 0..511
    int R2 = bx >> 4;                  // 0..31 (512-row block)
    int ch = bx & 15;                  // 512-col slice
    int w  = t >> 6, L = t & 63;
    int h  = L >> 5, l31 = L & 31;

    // stage the whole 64 KB B slice once (layout = global layout)
    {
        const unsigned char* src = Bb + ch * 65536 + t * 16;
        #pragma unroll
        for (int i = 0; i < 8; ++i)
            __builtin_amdgcn_global_load_lds(
                (const __attribute__((address_space(1))) void*)(src + i * 8192),
                (__attribute__((address_space(3))) void*)(&ldsB[t * 16 + i * 8192]),
                16, 0, 0);
    }

    // A fragments -> registers (overlaps the DMA): wave w owns 64 rows.
    i32x4 af[2][4];
    #pragma unroll
    for (int mi = 0; mi < 2; ++mi) {
        int mb = R2 * 16 + w * 2 + mi;
        #pragma unroll
        for (int ks = 0; ks < 4; ++ks)
            af[mi][ks] = *(const i32x4*)(Ab + (mb * 4 + ks) * 1024 + L * 16);
    }

    f32x16 zero16;
    #pragma unroll
    for (int r = 0; r < 16; ++r) zero16[r] = 0.f;

    unsigned minp32[32];
    #pragma unroll
    for (int kk = 0; kk < 32; ++kk) minp32[kk] = 0xFFFFFFFFu;

    __syncthreads();                   // B staged (drains the DMA); only barrier

    for (int nt = 0; nt < 8; ++nt) {
        f32x16 acc[2][2];
        {   // ks = 0: C operand = persistent zero16 (no acc-init VALU)
            i32x4 b0 = *(const i32x4*)(&ldsB[(nt * 8 + 0) * 1024 + L * 16]);
            i32x4 b1 = *(const i32x4*)(&ldsB[(nt * 8 + 4) * 1024 + L * 16]);
            #pragma unroll
            for (int mi = 0; mi < 2; ++mi) {
                acc[mi][0] = __builtin_amdgcn_mfma_scale_f32_32x32x64_f8f6f4(
                    up8(af[mi][0]), up8(b0), zero16, 4, 4, 0, 0x7F7F7F7F, 0, 0x7F7F7F7F);
                acc[mi][1] = __builtin_amdgcn_mfma_scale_f32_32x32x64_f8f6f4(
                    up8(af[mi][0]), up8(b1), zero16, 4, 4, 0, 0x7F7F7F7F, 0, 0x7F7F7F7F);
            }
        }
        #pragma unroll
        for (int ks = 1; ks < 4; ++ks) {
            i32x4 b0 = *(const i32x4*)(&ldsB[(nt * 8 + ks) * 1024 + L * 16]);
            i32x4 b1 = *(const i32x4*)(&ldsB[(nt * 8 + 4 + ks) * 1024 + L * 16]);
            #pragma unroll
            for (int mi = 0; mi < 2; ++mi) {
                acc[mi][0] = __builtin_amdgcn_mfma_scale_f32_32x32x64_f8f6f4(
                    up8(af[mi][ks]), up8(b0), acc[mi][0], 4, 4, 0, 0x7F7F7F7F, 0, 0x7F7F7F7F);
                acc[mi][1] = __builtin_amdgcn_mfma_scale_f32_32x32x64_f8f6f4(
                    up8(af[mi][ks]), up8(b1), acc[mi][1], 4, 4, 0, 0x7F7F7F7F, 0, 0x7F7F7F7F);
            }
        }

        int colb = ch * 512 + nt * 64 + l31;
        #pragma unroll
        for (int mi = 0; mi < 2; ++mi)
            #pragma unroll
            for (int r = 0; r < 16; ++r) {
                unsigned k0 = (__float_as_uint(512.0f - acc[mi][0][r]) & 0xFFFFE000u)
                            | (unsigned)colb;
                unsigned k1 = (__float_as_uint(512.0f - acc[mi][1][r]) & 0xFFFFE000u)
                            | (unsigned)(colb + 32);
                unsigned km = umin2(k0, k1);
                int kk = mi * 16 + r;
                minp32[kk] = umin2(minp32[kk], km);
            }
    }

    // reduce across the 32 column-lanes (xor<=16 stays within the h-half)
    #pragma unroll
    for (int ml = 1; ml <= 16; ml <<= 1)
        #pragma unroll
        for (int kk = 0; kk < 32; ++kk) {
            unsigned o = __shfl_xor(minp32[kk], ml);
            minp32[kk] = umin2(minp32[kk], o);
        }
    if (l31 == 0) {
        #pragma unroll
        for (int kk = 0; kk < 32; ++kk) {
            int mi = kk >> 4, reg = kk & 15;
            int row = R2 * 512 + w * 64 + mi * 32
                    + (reg & 3) + 8 * (reg >> 2) + 4 * h;
            atomicMin(&minP[row], minp32[kk]);
        }
    }
}

// ---------------------------------------------------------------- finalize
// out[b,d,h,w] = emb[idx[n]][d].  Loss computed ANALYTICALLY (no z reads):
// sum((zq-z)^2) = sum||z||^2 + sum(zq^2) - 2*dot, dot from the argmin key:
// dot = (512 - sc_q)/32768, sc_q = float(key & ~0x1FFF).
__global__ void finalize_kernel(const float* __restrict__ emb,
                                const float* __restrict__ zn2p,
                                const unsigned* __restrict__ minP,
                                float* __restrict__ out,
                                float* __restrict__ loss) {
    __shared__ float ez[32 * 257];
    __shared__ int   idxs[32];
    __shared__ float wsum[4];
    int t  = threadIdx.x;
    int bh = blockIdx.x;                 // b = bh>>5, h = bh&31
    float rterm = 0.f;
    if (t < 32) {
        int n = bh * 32 + t;
        unsigned key = minP[n];
        idxs[t] = (int)(key & 0x1FFFu);
        float sc_q = __uint_as_float(key & 0xFFFFE000u);
        float4 p0 = *(const float4*)(zn2p + n * 8);
        float4 p1 = *(const float4*)(zn2p + n * 8 + 4);
        float zn2 = p0.x + p0.y + p0.z + p0.w + p1.x + p1.y + p1.z + p1.w;
        rterm = zn2 - (512.0f - sc_q) * 6.103515625e-5f;   // - 2*dot
    }
    __syncthreads();
    {   // gather 32 embedding rows, coalesced along d, LDS-transposed
        int f = t & 63, rl = t >> 6;
        #pragma unroll
        for (int i = 0; i < 8; ++i) {
            int wl  = rl + i * 4;
            int idx = idxs[wl];
            float4 v = *(const float4*)(emb + idx * DDIM + f * 4);
            float* dst = &ez[wl * 257 + f * 4];
            dst[0] = v.x; dst[1] = v.y; dst[2] = v.z; dst[3] = v.w;
        }
    }
    __syncthreads();
    int wq = t & 31;                     // w
    int dg = t >> 5;                     // 0..7
    int off0 = (bh >> 5) * 262144 + (bh & 31) * 32 + wq;
    const float* ezrow = &ez[wq * 257];
    float lacc = rterm;
    #pragma unroll
    for (int it = 0; it < 32; ++it) {
        int d = it * 8 + dg;
        float zq = ezrow[d];
        out[off0 + d * 1024] = zq;
        lacc += zq * zq;                 // accumulates sum||e_idx||^2
    }
    #pragma unroll
    for (int ml = 1; ml <= 32; ml <<= 1) lacc += __shfl_xor(lacc, ml);
    if ((t & 63) == 0) wsum[t >> 6] = lacc;
    __syncthreads();
    if (t == 0) {
        float tot = wsum[0] + wsum[1] + wsum[2] + wsum[3];
        atomicAdd(loss, tot * (1.25f / (float)NELEM));
    }
}

// ---------------------------------------------------------------- launch
extern "C" void kernel_launch(void* const* d_in, const int* in_sizes, int n_in,
                              void* d_out, int out_size, void* d_ws, size_t ws_size,
                              hipStream_t stream) {
    const float* z   = (const float*)d_in[0];
    const float* emb = (const float*)d_in[1];
    float* out  = (float*)d_out;
    float* loss = out + NELEM;

    // ws: minP 64 KB + zn2p 512 KB. Big scratch (Ab 2MB @0, Bb 1MB @2MB)
    // overlaid on d_out (16.78 MB): consumed by gemm, then finalize overwrites.
    char* ws = (char*)d_ws;
    unsigned* minP = (unsigned*)ws;                           // 64 KB
    float* zn2p = (float*)(ws + 65536);                       // 512 KB
    unsigned char* Ab = (unsigned char*)d_out;                // 2 MB (2048 units)
    unsigned char* Bb = Ab + (size_t)NROWS * DDIM / 2;        // 1 MB (1024 units)

    hipLaunchKernelGGL(prep_kernel,        dim3(832), dim3(256), 0, stream,
                       z, emb, Ab, Bb, zn2p, minP, loss);
    hipLaunchKernelGGL(gemm_argmin_kernel, dim3(512), dim3(512), 0, stream,
                       Ab, Bb, minP);
    hipLaunchKernelGGL(finalize_kernel,    dim3(512), dim3(256), 0, stream,
                       emb, zn2p, minP, out, loss);
}